// Round 5
// baseline (127.926 us; speedup 1.0000x reference)
//
#include <hip/hip_runtime.h>

#define N_ 64
#define C_ 4
#define D_ 2048
#define K_ 64
#define O_ 256
#define L_ 1985
#define XPAD 2112          // padded x row (D_ + 64)
#define XCOPY 2116         // stride of shifted bf16 copies (shorts)
#define OPITCH 2020        // staging pitch (floats): mod 32 == 4 (bank spread)
#define NTILE 125          // ceil(L_/16)

typedef __attribute__((ext_vector_type(8))) short s16x8;
typedef __attribute__((ext_vector_type(4))) float f32x4;

// lgkmcnt-only barrier: global stores stay in flight across it
#define BAR_LGKM() do { \
    asm volatile("s_waitcnt lgkmcnt(0)\n\ts_barrier" ::: "memory"); \
    __builtin_amdgcn_sched_barrier(0); \
} while (0)

__device__ __forceinline__ unsigned short f2bf(float f) {
    union { float f; unsigned u; } v; v.f = f;
    unsigned u = v.u;
    u += 0x7fffu + ((u >> 16) & 1u);   // RNE
    return (unsigned short)(u >> 16);
}

__global__ __launch_bounds__(256) void prep_w(const float* __restrict__ w,
                                              unsigned short* __restrict__ wb,
                                              float* __restrict__ yn) {
    int o = blockIdx.x;
    int tid = threadIdx.x;
    int c = tid >> 6, k = tid & 63;
    size_t idx = (size_t)(o * C_ + c) * K_ + k;
    float v = w[idx];
    wb[idx] = f2bf(v);
    float s = v * v;
    for (int off = 32; off > 0; off >>= 1) s += __shfl_down(s, off, 64);
    if (k == 0) yn[o * C_ + c] = s;
}

// One block per (n,c), 16 waves. Stores of stage st-1 (held in regs) are
// interleaved 1-per-tile into stage st's compute so store issue is
// rate-matched to HBM drain instead of bursting at stage boundaries.
__global__ __launch_bounds__(1024) void shapelet_main(const float* __restrict__ x,
                                                      const unsigned short* __restrict__ wb,
                                                      const float* __restrict__ yn,
                                                      float* __restrict__ out) {
    __shared__ __align__(16) unsigned short xs[4][XCOPY];
    __shared__ float xn[D_];
    __shared__ __align__(16) float ost[16 * OPITCH];

    int nc = blockIdx.x;
    int c = nc & (C_ - 1);
    const float* xrow = x + (size_t)nc * D_;
    int tid = threadIdx.x;

    for (int i = tid; i < XPAD; i += 1024) ost[i] = (i < D_) ? xrow[i] : 0.f;
    __syncthreads();
    for (int i = tid; i < XCOPY; i += 1024) {
        #pragma unroll
        for (int s = 0; s < 4; ++s) {
            int idx = i + s;
            xs[s][i] = (idx < XPAD) ? f2bf(ost[idx]) : (unsigned short)0;
        }
    }
    for (int l = tid; l < D_; l += 1024) {
        float ssum = 0.f;
        #pragma unroll 16
        for (int k = 0; k < K_; ++k) { float v = ost[l + k]; ssum = fmaf(v, v, ssum); }
        xn[l] = ssum;
    }
    __syncthreads();

    int wave = tid >> 6, lane = tid & 63, lr = lane & 15, hi = lane >> 4;
    const unsigned short* xbase = &xs[lr & 3][(lr & ~3) + hi * 8];
    int dj = tid & 63;

    f32x4 rr[8];
    float tailv = 0.f;

    for (int st = 0; st < 16; ++st) {
        int o = st * 16 + lr;
        s16x8 wfr[2];
        #pragma unroll
        for (int kk = 0; kk < 2; ++kk)
            wfr[kk] = *reinterpret_cast<const s16x8*>(
                wb + ((size_t)o * C_ + c) * K_ + kk * 32 + hi * 8);
        float ynv = yn[o * C_ + c];
        float* gbprev = out + ((size_t)nc * O_ + (st - 1) * 16 + wave) * L_;

        // 8 iterations: compute tile (if valid) + 1 interleaved store of prev row
        #pragma unroll
        for (int i = 0; i < 8; ++i) {
            int t = wave + i * 16;
            if (t < NTILE) {
                int l0t = t * 16;
                f32x4 acc = {0.f, 0.f, 0.f, 0.f};
                #pragma unroll
                for (int kk = 0; kk < 2; ++kk) {
                    const unsigned long long* p =
                        (const unsigned long long*)(xbase + l0t + kk * 32);
                    union { unsigned long long u[2]; s16x8 v; } a;
                    a.u[0] = p[0]; a.u[1] = p[1];
                    acc = __builtin_amdgcn_mfma_f32_16x16x32_bf16(a.v, wfr[kk], acc, 0, 0, 0);
                }
                f32x4 xv = *reinterpret_cast<const f32x4*>(&xn[l0t + hi * 4]);
                f32x4 r;
                #pragma unroll
                for (int j = 0; j < 4; ++j)
                    r[j] = fmaxf(xv[j] + ynv - 2.f * acc[j], 0.f) * (1.f / (float)K_);
                *reinterpret_cast<f32x4*>(&ost[lr * OPITCH + l0t + hi * 4]) = r;
            }
            if (st > 0) {
                int pos = dj * 4 + i * 256;
                if (pos + 4 <= L_) __builtin_memcpy(gbprev + pos, &rr[i], 16);
            }
            __builtin_amdgcn_sched_barrier(0);   // keep store interleaved, not clustered
        }
        if (st > 0 && dj == 0) gbprev[L_ - 1] = tailv;
        BAR_LGKM();   // stage st fully staged in ost

        // pull stage st's row (this wave's row) into regs; ost then reusable
        const float* src = &ost[wave * OPITCH];
        #pragma unroll
        for (int q = 0; q < 8; ++q) {
            int pos = dj * 4 + q * 256;
            if (pos + 4 <= L_) rr[q] = *reinterpret_cast<const f32x4*>(src + pos);
        }
        tailv = (dj == 0) ? src[L_ - 1] : 0.f;
        BAR_LGKM();
    }

    // final drain: stage 15 rows
    float* gb = out + ((size_t)nc * O_ + 15 * 16 + wave) * L_;
    #pragma unroll
    for (int q = 0; q < 8; ++q) {
        int pos = dj * 4 + q * 256;
        if (pos + 4 <= L_) __builtin_memcpy(gb + pos, &rr[q], 16);
    }
    if (dj == 0) gb[L_ - 1] = tailv;
}

extern "C" void kernel_launch(void* const* d_in, const int* in_sizes, int n_in,
                              void* d_out, int out_size, void* d_ws, size_t ws_size,
                              hipStream_t stream) {
    const float* x = (const float*)d_in[0];
    const float* w = (const float*)d_in[1];
    float* out = (float*)d_out;

    unsigned short* wb = (unsigned short*)d_ws;                    // 128 KiB
    float* yn = (float*)((char*)d_ws + (size_t)O_ * C_ * K_ * 2);  // 4 KiB

    prep_w<<<O_, 256, 0, stream>>>(w, wb, yn);
    shapelet_main<<<N_ * C_, 1024, 0, stream>>>(x, wb, yn, out);
}

// Round 6
// 127.869 us; speedup vs baseline: 1.0004x; 1.0004x over previous
//
#include <hip/hip_runtime.h>

#define N_ 64
#define C_ 4
#define D_ 2048
#define K_ 64
#define O_ 256
#define L_ 1985
#define XPAD 2112          // padded x row (D_ + 64)
#define XCOPY 2116         // stride of shifted bf16 copies (shorts)
#define OPITCH 2020        // staging pitch (floats); row shifted by r%4 inside
#define NTILE 125          // ceil(L_/16)

typedef __attribute__((ext_vector_type(8))) short s16x8;
typedef __attribute__((ext_vector_type(4))) float f32x4;

// lgkmcnt-only barrier: global stores stay in flight across it
#define BAR_LGKM() do { \
    asm volatile("s_waitcnt lgkmcnt(0)\n\ts_barrier" ::: "memory"); \
    __builtin_amdgcn_sched_barrier(0); \
} while (0)

__device__ __forceinline__ unsigned short f2bf(float f) {
    union { float f; unsigned u; } v; v.f = f;
    unsigned u = v.u;
    u += 0x7fffu + ((u >> 16) & 1u);   // RNE
    return (unsigned short)(u >> 16);
}

__global__ __launch_bounds__(256) void prep_w(const float* __restrict__ w,
                                              unsigned short* __restrict__ wb,
                                              float* __restrict__ yn) {
    int o = blockIdx.x;
    int tid = threadIdx.x;
    int c = tid >> 6, k = tid & 63;
    size_t idx = (size_t)(o * C_ + c) * K_ + k;
    float v = w[idx];
    wb[idx] = f2bf(v);
    float s = v * v;
    for (int off = 32; off > 0; off >>= 1) s += __shfl_down(s, off, 64);
    if (k == 0) yn[o * C_ + c] = s;
}

// One block per (n,c), 16 waves, 16 stages of 16 o-rows. Staging rows are
// pre-shifted by r%4 so the drain does aligned ds_read_b128 AND the global
// store bodies are 128B-line-aligned full-coverage (no partial-line RMW).
__global__ __launch_bounds__(1024) void shapelet_main(const float* __restrict__ x,
                                                      const unsigned short* __restrict__ wb,
                                                      const float* __restrict__ yn,
                                                      float* __restrict__ out) {
    __shared__ __align__(16) unsigned short xs[4][XCOPY];
    __shared__ float xn[D_];
    __shared__ __align__(16) float ost[16 * OPITCH];

    int nc = blockIdx.x;
    int c = nc & (C_ - 1);
    const float* xrow = x + (size_t)nc * D_;
    int tid = threadIdx.x;

    // phase 0a: x row -> ost (fp32 scratch)
    for (int i = tid; i < XPAD; i += 1024) ost[i] = (i < D_) ? xrow[i] : 0.f;
    __syncthreads();
    // phase 0b: four 1-shifted bf16 copies + exact fp32 window norms
    for (int i = tid; i < XCOPY; i += 1024) {
        #pragma unroll
        for (int s = 0; s < 4; ++s) {
            int idx = i + s;
            xs[s][i] = (idx < XPAD) ? f2bf(ost[idx]) : (unsigned short)0;
        }
    }
    for (int l = tid; l < D_; l += 1024) {
        float ssum = 0.f;
        #pragma unroll 16
        for (int k = 0; k < K_; ++k) { float v = ost[l + k]; ssum = fmaf(v, v, ssum); }
        xn[l] = ssum;
    }
    __syncthreads();

    int wave = tid >> 6, lane = tid & 63, lr = lane & 15, hi = lane >> 4;
    const unsigned short* xbase = &xs[lr & 3][(lr & ~3) + hi * 8];
    int dj = lane;

    for (int st = 0; st < 16; ++st) {
        // ---- compute stage st: 16 o-rows x full L into ost (row lr shifted by lr&3) ----
        int o = st * 16 + lr;
        s16x8 wfr[2];
        #pragma unroll
        for (int kk = 0; kk < 2; ++kk)
            wfr[kk] = *reinterpret_cast<const s16x8*>(
                wb + ((size_t)o * C_ + c) * K_ + kk * 32 + hi * 8);
        float ynv = yn[o * C_ + c];

        for (int t = wave; t < NTILE; t += 16) {
            int l0t = t * 16;
            f32x4 acc = {0.f, 0.f, 0.f, 0.f};
            #pragma unroll
            for (int kk = 0; kk < 2; ++kk) {
                const unsigned long long* p =
                    (const unsigned long long*)(xbase + l0t + kk * 32);
                union { unsigned long long u[2]; s16x8 v; } a;
                a.u[0] = p[0]; a.u[1] = p[1];
                acc = __builtin_amdgcn_mfma_f32_16x16x32_bf16(a.v, wfr[kk], acc, 0, 0, 0);
            }
            f32x4 xv = *reinterpret_cast<const f32x4*>(&xn[l0t + hi * 4]);
            f32x4 r;
            #pragma unroll
            for (int j = 0; j < 4; ++j)
                r[j] = fmaxf(xv[j] + ynv - 2.f * acc[j], 0.f) * (1.f / (float)K_);
            // shifted staging write (runtime +lr&3 -> compiler emits safe b32s)
            __builtin_memcpy(&ost[lr * OPITCH + (lr & 3) + l0t + hi * 4], &r, 16);
        }
        BAR_LGKM();   // stage staged; global stores from prev stage still in flight

        // ---- drain: wave w streams row (16*st + w), line-aligned body ----
        int r_row = st * 16 + wave;
        float* gb = out + ((size_t)nc * O_ + r_row) * (size_t)L_;
        const float* src = &ost[wave * OPITCH + (wave & 3)];  // src[p] = row elem p
        int h = (32 - (r_row & 31)) & 31;                     // head elems to alignment

        if (dj < h) gb[dj] = src[dj];                         // scalar head
        #pragma unroll
        for (int q = 0; q < 7; ++q) {                         // 7 aligned 1KB chunks
            int p = h + q * 256 + dj * 4;
            f32x4 v = *reinterpret_cast<const f32x4*>(src + p);   // ds_read_b128
            *reinterpret_cast<f32x4*>(gb + p) = v;                // aligned dwordx4
        }
        int p0 = h + 1792;
        int nfull = (L_ - p0) >> 2;                           // 40..48 dwordx4 slots
        if (dj < nfull) {
            int p = p0 + dj * 4;
            f32x4 v = *reinterpret_cast<const f32x4*>(src + p);
            *reinterpret_cast<f32x4*>(gb + p) = v;
        }
        int tn = (L_ - p0) & 3;                               // 0..3 tail dwords
        if (dj < tn) {
            int p = p0 + nfull * 4 + dj;
            gb[p] = src[p];
        }
        BAR_LGKM();   // drain reads done -> ost reusable; stores stay in flight
    }
}

extern "C" void kernel_launch(void* const* d_in, const int* in_sizes, int n_in,
                              void* d_out, int out_size, void* d_ws, size_t ws_size,
                              hipStream_t stream) {
    const float* x = (const float*)d_in[0];
    const float* w = (const float*)d_in[1];
    float* out = (float*)d_out;

    unsigned short* wb = (unsigned short*)d_ws;                    // 128 KiB
    float* yn = (float*)((char*)d_ws + (size_t)O_ * C_ * K_ * 2);  // 4 KiB

    prep_w<<<O_, 256, 0, stream>>>(w, wb, yn);
    shapelet_main<<<N_ * C_, 1024, 0, stream>>>(x, wb, yn, out);
}